// Round 6
// baseline (553.653 us; speedup 1.0000x reference)
//
#include <hip/hip_runtime.h>
#include <cmath>
#include <cstdint>

#pragma clang fp contract(off)

#define B_ 2
#define N_ 65536
#define M_ 128
#define K_ 2048
#define S_ 6
#define NBLK 256          /* classify/compact blocks per batch */
#define CT 256            /* classify/compact threads per block */
#define FPS_T 256
#define NW 4              /* FPS_T / 64 waves */
#define RMAX 16           /* per-thread point slots */
#define CAP (FPS_T * RMAX)  /* 4096 points max for register fast path */

#define PI_F 3.14159265358979323846f
#define SS_F 1.0471975511965976f   /* (float)(2.0*pi/6) */

// Wave-wide max of 64-bit keys via DPP (VALU latency, not DS latency).
// Lane 63 holds the result. Identity: key==0 (bound_ctrl zero-fill loses).
__device__ __forceinline__ unsigned long long wave_max_u64_dpp(unsigned long long key) {
#define DPP_STEP(CTRL)                                                          \
    {                                                                           \
        unsigned lo = (unsigned)key, hi = (unsigned)(key >> 32);                \
        unsigned olo = (unsigned)__builtin_amdgcn_update_dpp(0, (int)lo, CTRL, 0xf, 0xf, true); \
        unsigned ohi = (unsigned)__builtin_amdgcn_update_dpp(0, (int)hi, CTRL, 0xf, 0xf, true); \
        unsigned long long o = ((unsigned long long)ohi << 32) | olo;           \
        if (o > key) key = o;                                                   \
    }
    DPP_STEP(0x111)  /* row_shr:1  */
    DPP_STEP(0x112)  /* row_shr:2  */
    DPP_STEP(0x114)  /* row_shr:4  */
    DPP_STEP(0x118)  /* row_shr:8  */
    DPP_STEP(0x142)  /* row_bcast:15 */
    DPP_STEP(0x143)  /* row_bcast:31 */
#undef DPP_STEP
    return key;
}

// ------------------------------------------------------------ classify ----
__global__ __launch_bounds__(CT)
void k_classify(const float* __restrict__ points, const float* __restrict__ rois,
                int* __restrict__ sec_id, int* __restrict__ blkcnt) {
    __shared__ float4 sroi[M_];
    __shared__ int lc[8];
    int blk = blockIdx.x;
    int gid = blk * CT + threadIdx.x;
    int b = gid >> 16;                       // N_ = 65536
    if (threadIdx.x < M_) {
        const float* r = rois + ((size_t)b * M_ + threadIdx.x) * 7;
        float cz = r[2] + r[5] * 0.5f;       // geometric center
        float hx = r[3] * 0.5f, hy = r[4] * 0.5f, hz = r[5] * 0.5f;
        sroi[threadIdx.x] = make_float4(r[0], r[1], cz, sqrtf((hx*hx + hy*hy) + hz*hz));
    }
    if (threadIdx.x < 8) lc[threadIdx.x] = 0;
    __syncthreads();

    const float* p = points + (size_t)gid * 3;
    float px = p[0], py = p[1], pz = p[2];
    float best = 1e30f; int bi = 0;
    for (int m = 0; m < M_; m++) {
        float4 c = sroi[m];
        float dx = px - c.x, dy = py - c.y, dz = pz - c.z;
        float d = sqrtf((dx*dx + dy*dy) + dz*dz);
        if (d < best) { best = d; bi = m; }  // strict < : first argmin
    }
    bool valid = best < (sroi[bi].w + 1.6f);

    float a = atan2f(py, px) + PI_F;
    float fs = floorf(a / SS_F);
    fs = fminf(fmaxf(fs, 0.0f), 6.0f);
    int sec = (int)fs;

    sec_id[gid] = valid ? sec : -1;
    if (valid) atomicAdd(&lc[sec], 1);
    __syncthreads();
    if (threadIdx.x < 8) blkcnt[blk * 8 + threadIdx.x] = lc[threadIdx.x];
}

// ---------------------------------------------------------------- plan ----
__global__ void k_plan(const int* __restrict__ blkcnt, int* __restrict__ bbase,
                       int* __restrict__ cnt, int* __restrict__ offv,
                       int* __restrict__ n_needed, int* __restrict__ sec_base,
                       int* __restrict__ s_total) {
    __shared__ int scnt[2][8];
    int t = threadIdx.x;
    if (t < 16) scnt[t >> 3][t & 7] = 0;
    __syncthreads();
    if (t < 14) {
        int b = t / 7, s = t % 7;
        int run = 0;
        for (int j = 0; j < NBLK; j++) {
            int blk = b * NBLK + j;
            int c = blkcnt[blk * 8 + s];
            if (s < 6) bbase[blk * 6 + s] = run;
            run += c;
        }
        scnt[b][s] = run;
        cnt[b * 8 + s] = run;
    }
    __syncthreads();
    if (t < B_) {
        int b = t;
        int total = 0;
        for (int s = 0; s < 7; s++) total += scnt[b][s];
        if (total < 1) total = 1;
        int sb = 0, snk = 0;
        for (int s = 0; s < 6; s++) {
            int cs = scnt[b][s];
            int nk = (int)ceilf((float)cs * 2048.0f / (float)total);  // f32 semantics
            if (nk > cs) nk = cs;
            offv[b * 6 + s] = snk;
            int need = 0;
            if (snk < K_) { need = K_ - snk; if (need > nk) need = nk; }
            n_needed[b * 6 + s] = need;
            sec_base[b * 6 + s] = sb;
            sb += cs; snk += nk;
        }
        s_total[b] = (snk < 1) ? 1 : snk;
    }
}

// ------------------------------------------------------------- compact ----
__global__ __launch_bounds__(CT)
void k_compact(const float* __restrict__ points, const int* __restrict__ sec_id,
               const int* __restrict__ sec_base, const int* __restrict__ bbase,
               int* __restrict__ comp_idx, float4* __restrict__ comp_xyz) {
    __shared__ int lc[4 * 6];
    __shared__ int sbase[6], blkb[6];
    int blk = blockIdx.x;
    int b = blk >> 8;                         // NBLK = 256 blocks per batch
    int tid = threadIdx.x, lane = tid & 63, wid = tid >> 6;
    if (tid < 6) sbase[tid] = sec_base[b * 6 + tid];
    else if (tid >= 64 && tid < 70) blkb[tid - 64] = bbase[blk * 6 + (tid - 64)];
    int gid = blk * CT + tid;
    int sec = sec_id[gid];
    unsigned long long mymask = 0;
    for (int s = 0; s < 6; s++) {
        unsigned long long m = __ballot(sec == s);
        if (sec == s) mymask = m;
        if (lane == 0) lc[wid * 6 + s] = __popcll(m);
    }
    __syncthreads();
    if (sec >= 0 && sec < 6) {
        int woff = 0;
        for (int w = 0; w < wid; w++) woff += lc[w * 6 + sec];
        int rank = __popcll(mymask & ((1ull << lane) - 1ull));
        int addr = b * N_ + sbase[sec] + blkb[sec] + woff + rank;
        const float* p = points + (size_t)gid * 3;
        comp_idx[addr] = gid & (N_ - 1);
        comp_xyz[addr] = make_float4(p[0], p[1], p[2], 0.0f);
    }
}

// ----------------------------------------------------------------- fps ----
// one block (256 thr, 4 waves) per (b,s). Points + dmin in registers, xyz
// mirror in LDS for winner broadcast. Per pick: key-only DPP wave argmax,
// ONE barrier (double-buffered 4-entry slot), no global reads on the chain.
// Spill control: __launch_bounds__(256,3) caps VGPR ~168 (R5's (256,1)
// allowed a 252-reg + 400 KB-scratch allocation); dist loop split into
// groups of 4 slots with sched_barrier(0) between groups to bound live
// ranges; staging loads grouped the same way.
__global__ __launch_bounds__(FPS_T, 3)
void k_fps(const int* __restrict__ cnt, const int* __restrict__ sec_base,
           const int* __restrict__ offv, const int* __restrict__ n_needed,
           const float4* __restrict__ comp_xyz,
           float* __restrict__ dmin_g, int* __restrict__ buf) {
    __shared__ float4 sxyz[CAP];
    __shared__ unsigned long long skey[2][NW];
    int b = blockIdx.x / S_, s = blockIdx.x % S_;
    int need = n_needed[b * 6 + s];
    if (need <= 0) return;
    int cs = cnt[b * 8 + s];
    int base = b * N_ + sec_base[b * 6 + s];
    const float4* cxyz = comp_xyz + base;
    int off = b * K_ + offv[b * 6 + s];
    int tid = threadIdx.x, lane = tid & 63, wid = tid >> 6;

    if (tid == 0) buf[off] = base;            // first pick = first point
    if (cs <= CAP) {
        // ---- fast path: points + dmin in registers, xyz mirror in LDS ----
        float px[RMAX], py[RMAX], pz[RMAX], dmv[RMAX];
        #pragma unroll
        for (int g = 0; g < RMAX / 4; g++) {
            #pragma unroll
            for (int rr = 0; rr < 4; rr++) {
                const int r = g * 4 + rr;
                if (r * FPS_T < cs) {
                    int i = tid + r * FPS_T;
                    if (i < cs) {
                        float4 q = cxyz[i];
                        sxyz[i] = q;
                        px[r] = q.x; py[r] = q.y; pz[r] = q.z;
                        dmv[r] = 1e10f;
                    }
                }
            }
            __builtin_amdgcn_sched_barrier(0);
        }
        __syncthreads();
        if (need == 1) return;
        float4 l4 = sxyz[0];
        float lx = l4.x, ly = l4.y, lz = l4.z;

        #pragma unroll 1
        for (int k = 1; k < need; k++) {
            unsigned long long key = 0;
            #pragma unroll
            for (int g = 0; g < RMAX / 4; g++) {
                unsigned long long gkey = 0;
                #pragma unroll
                for (int rr = 0; rr < 4; rr++) {
                    const int r = g * 4 + rr;
                    if (r * FPS_T < cs) {
                        int i = tid + r * FPS_T;
                        if (i < cs) {
                            float dx = px[r] - lx, dy = py[r] - ly, dz = pz[r] - lz;
                            float d = (dx*dx + dy*dy) + dz*dz;    // contract off
                            float nd = fminf(dmv[r], d);
                            dmv[r] = nd;
                            unsigned long long kk =
                                ((unsigned long long)__float_as_uint(nd) << 32) | (unsigned)(~(unsigned)i);
                            if (kk > gkey) gkey = kk;             // max val, tie -> min i
                        }
                    }
                }
                if (gkey > key) key = gkey;
                __builtin_amdgcn_sched_barrier(0);
            }
            key = wave_max_u64_dpp(key);
            int par = k & 1;
            if (lane == 63) skey[par][wid] = key;
            __syncthreads();
            unsigned long long bk = skey[par][0];
            if (skey[par][1] > bk) bk = skey[par][1];
            if (skey[par][2] > bk) bk = skey[par][2];
            if (skey[par][3] > bk) bk = skey[par][3];
            int bix = (int)(~(unsigned)(bk & 0xFFFFFFFFull));
            if (tid == 0) buf[off + k] = base + bix;
            float4 n4 = sxyz[bix];                            // LDS broadcast
            lx = n4.x; ly = n4.y; lz = n4.z;
        }
    } else {
        // ---- fallback: dmin in global (not taken for this data: cs<=CAP) ----
        float* dm = dmin_g + base;
        __syncthreads();
        if (need == 1) return;
        float4 f0 = cxyz[0];
        float lx = f0.x, ly = f0.y, lz = f0.z;
        #pragma unroll 1
        for (int k = 1; k < need; k++) {
            unsigned long long key = 0;
            #pragma unroll 1
            for (int i = tid; i < cs; i += FPS_T) {
                float4 q = cxyz[i];
                float dx = q.x - lx, dy = q.y - ly, dz = q.z - lz;
                float d = (dx*dx + dy*dy) + dz*dz;
                float prev = (k == 1) ? 1e10f : dm[i];
                float nd = fminf(prev, d);
                dm[i] = nd;
                unsigned long long kk =
                    ((unsigned long long)__float_as_uint(nd) << 32) | (unsigned)(~(unsigned)i);
                if (kk > key) key = kk;
            }
            key = wave_max_u64_dpp(key);
            int par = k & 1;
            if (lane == 63) skey[par][wid] = key;
            __syncthreads();
            unsigned long long bk = skey[par][0];
            if (skey[par][1] > bk) bk = skey[par][1];
            if (skey[par][2] > bk) bk = skey[par][2];
            if (skey[par][3] > bk) bk = skey[par][3];
            int bix = (int)(~(unsigned)(bk & 0xFFFFFFFFull));
            if (tid == 0) buf[off + k] = base + bix;
            float4 n4 = cxyz[bix];                            // rare path
            lx = n4.x; ly = n4.y; lz = n4.z;
        }
    }
}

// ----------------------------------------------------------------- out ----
__global__ void k_out(const float* __restrict__ points, const int* __restrict__ buf,
                      const int* __restrict__ comp_idx, const int* __restrict__ s_total,
                      float* __restrict__ out) {
    int i = blockIdx.x * 256 + threadIdx.x;
    if (i >= B_ * K_) return;
    int b = i / K_, j = i % K_;
    int st = s_total[b];
    int g = buf[b * K_ + (j % st)];          // compacted global slot
    int idx = comp_idx[g];                   // original point index
    const float* p = points + ((size_t)b * N_ + idx) * 3;
    float* o = out + (size_t)i * 3;
    o[0] = p[0]; o[1] = p[1]; o[2] = p[2];
}

// -------------------------------------------------------------- launch ----
extern "C" void kernel_launch(void* const* d_in, const int* in_sizes, int n_in,
                              void* d_out, int out_size, void* d_ws, size_t ws_size,
                              hipStream_t stream) {
    const float* points = (const float*)d_in[0];   // [B,N,3]
    const float* rois   = (const float*)d_in[1];   // [B,M,7]
    float* out = (float*)d_out;                    // [B,K,3]

    char* w = (char*)d_ws;
    auto carve = [&](size_t bytes) -> char* {
        char* p = w; w += (bytes + 255) & ~(size_t)255; return p;
    };
    int*    sec_id   = (int*)   carve((size_t)B_ * N_ * sizeof(int));
    int*    blkcnt   = (int*)   carve((size_t)B_ * NBLK * 8 * sizeof(int));
    int*    bbase    = (int*)   carve((size_t)B_ * NBLK * 6 * sizeof(int));
    int*    cnt      = (int*)   carve((size_t)B_ * 8 * sizeof(int));
    int*    offv     = (int*)   carve((size_t)B_ * 6 * sizeof(int));
    int*    n_needed = (int*)   carve((size_t)B_ * 6 * sizeof(int));
    int*    sec_base = (int*)   carve((size_t)B_ * 6 * sizeof(int));
    int*    s_total  = (int*)   carve((size_t)B_ * sizeof(int));
    int*    buf      = (int*)   carve((size_t)B_ * K_ * sizeof(int));
    int*    comp_idx = (int*)   carve((size_t)B_ * N_ * sizeof(int));
    float4* comp_xyz = (float4*)carve((size_t)B_ * N_ * sizeof(float4));
    float*  dmin_g   = (float*) carve((size_t)B_ * N_ * sizeof(float));

    hipLaunchKernelGGL(k_classify, dim3(B_ * NBLK), dim3(CT), 0, stream,
                       points, rois, sec_id, blkcnt);
    hipLaunchKernelGGL(k_plan, dim3(1), dim3(64), 0, stream,
                       blkcnt, bbase, cnt, offv, n_needed, sec_base, s_total);
    hipLaunchKernelGGL(k_compact, dim3(B_ * NBLK), dim3(CT), 0, stream,
                       points, sec_id, sec_base, bbase, comp_idx, comp_xyz);
    hipLaunchKernelGGL(k_fps, dim3(B_ * S_), dim3(FPS_T), 0, stream,
                       cnt, sec_base, offv, n_needed, comp_xyz, dmin_g, buf);
    hipLaunchKernelGGL(k_out, dim3((B_ * K_ + 255) / 256), dim3(256), 0, stream,
                       points, buf, comp_idx, s_total, out);
}

// Round 7
// 473.641 us; speedup vs baseline: 1.1689x; 1.1689x over previous
//
#include <hip/hip_runtime.h>
#include <cmath>
#include <cstdint>

#pragma clang fp contract(off)

#define B_ 2
#define N_ 65536
#define M_ 128
#define K_ 2048
#define S_ 6
#define NBLK 256          /* classify/compact blocks per batch */
#define CT 256            /* classify/compact threads per block */
#define FPS_T 256
#define NW 4              /* FPS_T / 64 waves */
#define RMAX 16           /* per-thread point slots */
#define CAP (FPS_T * RMAX)  /* 4096 points max for register fast path */

#define PI_F 3.14159265358979323846f
#define SS_F 1.0471975511965976f   /* (float)(2.0*pi/6) */

// Wave-wide max of 64-bit keys via DPP (VALU latency, not DS latency).
// Lane 63 holds the result. Identity: key==0 (bound_ctrl zero-fill loses).
__device__ __forceinline__ unsigned long long wave_max_u64_dpp(unsigned long long key) {
#define DPP_STEP(CTRL)                                                          \
    {                                                                           \
        unsigned lo = (unsigned)key, hi = (unsigned)(key >> 32);                \
        unsigned olo = (unsigned)__builtin_amdgcn_update_dpp(0, (int)lo, CTRL, 0xf, 0xf, true); \
        unsigned ohi = (unsigned)__builtin_amdgcn_update_dpp(0, (int)hi, CTRL, 0xf, 0xf, true); \
        unsigned long long o = ((unsigned long long)ohi << 32) | olo;           \
        if (o > key) key = o;                                                   \
    }
    DPP_STEP(0x111)  /* row_shr:1  */
    DPP_STEP(0x112)  /* row_shr:2  */
    DPP_STEP(0x114)  /* row_shr:4  */
    DPP_STEP(0x118)  /* row_shr:8  */
    DPP_STEP(0x142)  /* row_bcast:15 */
    DPP_STEP(0x143)  /* row_bcast:31 */
#undef DPP_STEP
    return key;
}

// ------------------------------------------------------------ classify ----
__global__ __launch_bounds__(CT)
void k_classify(const float* __restrict__ points, const float* __restrict__ rois,
                int* __restrict__ sec_id, int* __restrict__ blkcnt) {
    __shared__ float4 sroi[M_];
    __shared__ int lc[8];
    int blk = blockIdx.x;
    int gid = blk * CT + threadIdx.x;
    int b = gid >> 16;                       // N_ = 65536
    if (threadIdx.x < M_) {
        const float* r = rois + ((size_t)b * M_ + threadIdx.x) * 7;
        float cz = r[2] + r[5] * 0.5f;       // geometric center
        float hx = r[3] * 0.5f, hy = r[4] * 0.5f, hz = r[5] * 0.5f;
        sroi[threadIdx.x] = make_float4(r[0], r[1], cz, sqrtf((hx*hx + hy*hy) + hz*hz));
    }
    if (threadIdx.x < 8) lc[threadIdx.x] = 0;
    __syncthreads();

    const float* p = points + (size_t)gid * 3;
    float px = p[0], py = p[1], pz = p[2];
    float best = 1e30f; int bi = 0;
    for (int m = 0; m < M_; m++) {
        float4 c = sroi[m];
        float dx = px - c.x, dy = py - c.y, dz = pz - c.z;
        float d = sqrtf((dx*dx + dy*dy) + dz*dz);
        if (d < best) { best = d; bi = m; }  // strict < : first argmin
    }
    bool valid = best < (sroi[bi].w + 1.6f);

    float a = atan2f(py, px) + PI_F;
    float fs = floorf(a / SS_F);
    fs = fminf(fmaxf(fs, 0.0f), 6.0f);
    int sec = (int)fs;

    sec_id[gid] = valid ? sec : -1;
    if (valid) atomicAdd(&lc[sec], 1);
    __syncthreads();
    if (threadIdx.x < 8) blkcnt[blk * 8 + threadIdx.x] = lc[threadIdx.x];
}

// ---------------------------------------------------------------- plan ----
__global__ void k_plan(const int* __restrict__ blkcnt, int* __restrict__ bbase,
                       int* __restrict__ cnt, int* __restrict__ offv,
                       int* __restrict__ n_needed, int* __restrict__ sec_base,
                       int* __restrict__ s_total) {
    __shared__ int scnt[2][8];
    int t = threadIdx.x;
    if (t < 16) scnt[t >> 3][t & 7] = 0;
    __syncthreads();
    if (t < 14) {
        int b = t / 7, s = t % 7;
        int run = 0;
        for (int j = 0; j < NBLK; j++) {
            int blk = b * NBLK + j;
            int c = blkcnt[blk * 8 + s];
            if (s < 6) bbase[blk * 6 + s] = run;
            run += c;
        }
        scnt[b][s] = run;
        cnt[b * 8 + s] = run;
    }
    __syncthreads();
    if (t < B_) {
        int b = t;
        int total = 0;
        for (int s = 0; s < 7; s++) total += scnt[b][s];
        if (total < 1) total = 1;
        int sb = 0, snk = 0;
        for (int s = 0; s < 6; s++) {
            int cs = scnt[b][s];
            int nk = (int)ceilf((float)cs * 2048.0f / (float)total);  // f32 semantics
            if (nk > cs) nk = cs;
            offv[b * 6 + s] = snk;
            int need = 0;
            if (snk < K_) { need = K_ - snk; if (need > nk) need = nk; }
            n_needed[b * 6 + s] = need;
            sec_base[b * 6 + s] = sb;
            sb += cs; snk += nk;
        }
        s_total[b] = (snk < 1) ? 1 : snk;
    }
}

// ------------------------------------------------------------- compact ----
__global__ __launch_bounds__(CT)
void k_compact(const float* __restrict__ points, const int* __restrict__ sec_id,
               const int* __restrict__ sec_base, const int* __restrict__ bbase,
               int* __restrict__ comp_idx, float4* __restrict__ comp_xyz) {
    __shared__ int lc[4 * 6];
    __shared__ int sbase[6], blkb[6];
    int blk = blockIdx.x;
    int b = blk >> 8;                         // NBLK = 256 blocks per batch
    int tid = threadIdx.x, lane = tid & 63, wid = tid >> 6;
    if (tid < 6) sbase[tid] = sec_base[b * 6 + tid];
    else if (tid >= 64 && tid < 70) blkb[tid - 64] = bbase[blk * 6 + (tid - 64)];
    int gid = blk * CT + tid;
    int sec = sec_id[gid];
    unsigned long long mymask = 0;
    for (int s = 0; s < 6; s++) {
        unsigned long long m = __ballot(sec == s);
        if (sec == s) mymask = m;
        if (lane == 0) lc[wid * 6 + s] = __popcll(m);
    }
    __syncthreads();
    if (sec >= 0 && sec < 6) {
        int woff = 0;
        for (int w = 0; w < wid; w++) woff += lc[w * 6 + sec];
        int rank = __popcll(mymask & ((1ull << lane) - 1ull));
        int addr = b * N_ + sbase[sec] + blkb[sec] + woff + rank;
        const float* p = points + (size_t)gid * 3;
        comp_idx[addr] = gid & (N_ - 1);
        comp_xyz[addr] = make_float4(p[0], p[1], p[2], 0.0f);
    }
}

// ----------------------------------------------------------------- fps ----
// one block (256 thr, 4 waves) per (b,s). Points + dmin in registers, xyz
// mirror in LDS for winner broadcast. Per pick: key-only DPP wave argmax,
// ONE barrier (double-buffered 4-entry slot). ZERO global memory ops inside
// the pick loop: winner indices buffered in pick_lds (ds_write, drained by
// next iteration's barrier for free — a per-pick global store forces the
// compiler's `s_waitcnt vmcnt(0)` before s_barrier, ~hundreds of cyc/pick),
// then one coalesced buf writeback after the loop.
__global__ __launch_bounds__(FPS_T, 3)
void k_fps(const int* __restrict__ cnt, const int* __restrict__ sec_base,
           const int* __restrict__ offv, const int* __restrict__ n_needed,
           const float4* __restrict__ comp_xyz,
           float* __restrict__ dmin_g, int* __restrict__ buf) {
    __shared__ float4 sxyz[CAP];
    __shared__ int pick_lds[K_];
    __shared__ unsigned long long skey[2][NW];
    int b = blockIdx.x / S_, s = blockIdx.x % S_;
    int need = n_needed[b * 6 + s];
    if (need <= 0) return;
    int cs = cnt[b * 8 + s];
    int base = b * N_ + sec_base[b * 6 + s];
    const float4* cxyz = comp_xyz + base;
    int off = b * K_ + offv[b * 6 + s];
    int tid = threadIdx.x, lane = tid & 63, wid = tid >> 6;

    if (cs <= CAP) {
        // ---- fast path: points + dmin in registers, xyz mirror in LDS ----
        float px[RMAX], py[RMAX], pz[RMAX], dmv[RMAX];
        #pragma unroll
        for (int r = 0; r < RMAX; r++) {
            if (r * FPS_T < cs) {
                int i = tid + r * FPS_T;
                if (i < cs) {
                    float4 q = cxyz[i];
                    sxyz[i] = q;
                    px[r] = q.x; py[r] = q.y; pz[r] = q.z;
                    dmv[r] = 1e10f;
                }
            }
        }
        if (tid == 0) pick_lds[0] = 0;       // first pick = first point
        __syncthreads();
        float4 l4 = sxyz[0];
        float lx = l4.x, ly = l4.y, lz = l4.z;

        #pragma unroll 1
        for (int k = 1; k < need; k++) {
            unsigned long long key = 0;
            #pragma unroll
            for (int r = 0; r < RMAX; r++) {
                if (r * FPS_T < cs) {
                    int i = tid + r * FPS_T;
                    if (i < cs) {
                        float dx = px[r] - lx, dy = py[r] - ly, dz = pz[r] - lz;
                        float d = (dx*dx + dy*dy) + dz*dz;    // contract off
                        float nd = fminf(dmv[r], d);
                        dmv[r] = nd;
                        unsigned long long kk =
                            ((unsigned long long)__float_as_uint(nd) << 32) | (unsigned)(~(unsigned)i);
                        if (kk > key) key = kk;               // max val, tie -> min i
                    }
                }
            }
            key = wave_max_u64_dpp(key);
            int par = k & 1;
            if (lane == 63) skey[par][wid] = key;
            __syncthreads();
            unsigned long long bk = skey[par][0];
            if (skey[par][1] > bk) bk = skey[par][1];
            if (skey[par][2] > bk) bk = skey[par][2];
            if (skey[par][3] > bk) bk = skey[par][3];
            int bix = (int)(~(unsigned)(bk & 0xFFFFFFFFull));
            if (tid == 0) pick_lds[k] = bix;                  // LDS, not global
            float4 n4 = sxyz[bix];                            // LDS broadcast
            lx = n4.x; ly = n4.y; lz = n4.z;
        }
        __syncthreads();
        // coalesced writeback of all picks
        #pragma unroll 1
        for (int i = tid; i < need; i += FPS_T)
            buf[off + i] = base + pick_lds[i];
    } else {
        // ---- fallback: dmin in global (not taken for this data: cs<=CAP) ----
        float* dm = dmin_g + base;
        if (tid == 0) pick_lds[0] = 0;
        __syncthreads();
        float4 f0 = cxyz[0];
        float lx = f0.x, ly = f0.y, lz = f0.z;
        #pragma unroll 1
        for (int k = 1; k < need; k++) {
            unsigned long long key = 0;
            #pragma unroll 1
            for (int i = tid; i < cs; i += FPS_T) {
                float4 q = cxyz[i];
                float dx = q.x - lx, dy = q.y - ly, dz = q.z - lz;
                float d = (dx*dx + dy*dy) + dz*dz;
                float prev = (k == 1) ? 1e10f : dm[i];
                float nd = fminf(prev, d);
                dm[i] = nd;
                unsigned long long kk =
                    ((unsigned long long)__float_as_uint(nd) << 32) | (unsigned)(~(unsigned)i);
                if (kk > key) key = kk;
            }
            key = wave_max_u64_dpp(key);
            int par = k & 1;
            if (lane == 63) skey[par][wid] = key;
            __syncthreads();
            unsigned long long bk = skey[par][0];
            if (skey[par][1] > bk) bk = skey[par][1];
            if (skey[par][2] > bk) bk = skey[par][2];
            if (skey[par][3] > bk) bk = skey[par][3];
            int bix = (int)(~(unsigned)(bk & 0xFFFFFFFFull));
            if (tid == 0) pick_lds[k] = bix;
            float4 n4 = cxyz[bix];                            // rare path
            lx = n4.x; ly = n4.y; lz = n4.z;
        }
        __syncthreads();
        #pragma unroll 1
        for (int i = tid; i < need; i += FPS_T)
            buf[off + i] = base + pick_lds[i];
    }
}

// ----------------------------------------------------------------- out ----
__global__ void k_out(const float* __restrict__ points, const int* __restrict__ buf,
                      const int* __restrict__ comp_idx, const int* __restrict__ s_total,
                      float* __restrict__ out) {
    int i = blockIdx.x * 256 + threadIdx.x;
    if (i >= B_ * K_) return;
    int b = i / K_, j = i % K_;
    int st = s_total[b];
    int g = buf[b * K_ + (j % st)];          // compacted global slot
    int idx = comp_idx[g];                   // original point index
    const float* p = points + ((size_t)b * N_ + idx) * 3;
    float* o = out + (size_t)i * 3;
    o[0] = p[0]; o[1] = p[1]; o[2] = p[2];
}

// -------------------------------------------------------------- launch ----
extern "C" void kernel_launch(void* const* d_in, const int* in_sizes, int n_in,
                              void* d_out, int out_size, void* d_ws, size_t ws_size,
                              hipStream_t stream) {
    const float* points = (const float*)d_in[0];   // [B,N,3]
    const float* rois   = (const float*)d_in[1];   // [B,M,7]
    float* out = (float*)d_out;                    // [B,K,3]

    char* w = (char*)d_ws;
    auto carve = [&](size_t bytes) -> char* {
        char* p = w; w += (bytes + 255) & ~(size_t)255; return p;
    };
    int*    sec_id   = (int*)   carve((size_t)B_ * N_ * sizeof(int));
    int*    blkcnt   = (int*)   carve((size_t)B_ * NBLK * 8 * sizeof(int));
    int*    bbase    = (int*)   carve((size_t)B_ * NBLK * 6 * sizeof(int));
    int*    cnt      = (int*)   carve((size_t)B_ * 8 * sizeof(int));
    int*    offv     = (int*)   carve((size_t)B_ * 6 * sizeof(int));
    int*    n_needed = (int*)   carve((size_t)B_ * 6 * sizeof(int));
    int*    sec_base = (int*)   carve((size_t)B_ * 6 * sizeof(int));
    int*    s_total  = (int*)   carve((size_t)B_ * sizeof(int));
    int*    buf      = (int*)   carve((size_t)B_ * K_ * sizeof(int));
    int*    comp_idx = (int*)   carve((size_t)B_ * N_ * sizeof(int));
    float4* comp_xyz = (float4*)carve((size_t)B_ * N_ * sizeof(float4));
    float*  dmin_g   = (float*) carve((size_t)B_ * N_ * sizeof(float));

    hipLaunchKernelGGL(k_classify, dim3(B_ * NBLK), dim3(CT), 0, stream,
                       points, rois, sec_id, blkcnt);
    hipLaunchKernelGGL(k_plan, dim3(1), dim3(64), 0, stream,
                       blkcnt, bbase, cnt, offv, n_needed, sec_base, s_total);
    hipLaunchKernelGGL(k_compact, dim3(B_ * NBLK), dim3(CT), 0, stream,
                       points, sec_id, sec_base, bbase, comp_idx, comp_xyz);
    hipLaunchKernelGGL(k_fps, dim3(B_ * S_), dim3(FPS_T), 0, stream,
                       cnt, sec_base, offv, n_needed, comp_xyz, dmin_g, buf);
    hipLaunchKernelGGL(k_out, dim3((B_ * K_ + 255) / 256), dim3(256), 0, stream,
                       points, buf, comp_idx, s_total, out);
}